// Round 5
// baseline (199.362 us; speedup 1.0000x reference)
//
#include <hip/hip_runtime.h>
#include <hip/hip_bf16.h>
#include <math.h>

#define NB 2
#define NN 4096
#define FIN 128
#define FOUT 64
#define LALPHA 0.2f
#define NJC 16            // j-chunks per row (chunk = 256 j)

// ws float-offsets
#define WS_S1   0                          // NB*NN
#define WS_S2   (NB*NN)                    // NB*NN
#define WS_WHT  (2*NB*NN)                  // NB*FOUT*NN ushorts = NB*FOUT*NN/2 floats
#define WS_LSL  (2*NB*NN + NB*FOUT*NN/2)   // 256 rt * NJC * 32 floats (l partials)
#define WS_SLAB (WS_LSL + 256*NJC*32)      // 256 rt * NJC * 2048 floats (acc partials)
#define WS_PK   (WS_SLAB + 256*NJC*2048)   // NN*NN/32 uints = NN*NN/32 floats (bitmask)

typedef __attribute__((ext_vector_type(8))) short short8;
typedef __attribute__((ext_vector_type(4))) float f32x4;

static __device__ inline unsigned int pack2bf(float x, float y) {
    float2 f2; f2.x = x; f2.y = y;
    __hip_bfloat162 pp = __float22bfloat162_rn(f2);
    return *reinterpret_cast<unsigned int*>(&pp);
}

// K0: pack adj (int32 0/1, 64 MB) -> bitmask (2 MB). Wave reads 64 consecutive
// ints coalesced; __ballot gives the 64-bit mask (bit i = lane i). Streaming,
// latency-tolerant (64 independent rounds per wave).
__global__ __launch_bounds__(256) void k0_pack(const int* __restrict__ adj,
                                               float* __restrict__ ws) {
    unsigned long long* dst = (unsigned long long*)(ws + WS_PK);
    const int gwave = blockIdx.x * 4 + (threadIdx.x >> 6);
    const int lane  = threadIdx.x & 63;
    const size_t base = (size_t)gwave * 64 * 64;     // flat element base
#pragma unroll 4
    for (int r = 0; r < 64; ++r) {
        int av = adj[base + (size_t)r * 64 + lane];
        unsigned long long m = __ballot(av > 0);
        if (lane == 0) dst[(size_t)gwave * 64 + r] = m;
    }
}

// K1: Wh = h@W ; s1 = Wh@a1 ; s2 = Wh@a2 ; WhT bf16 [b][f][j].
// One wave per (b,row); lane = out feature. Block = 4 waves = 4 consecutive rows.
__global__ __launch_bounds__(256) void k1_proj(const float* __restrict__ h,
                                               const float* __restrict__ W,
                                               const float* __restrict__ a,
                                               float* __restrict__ ws) {
    __shared__ float tbuf[4][68];
    int gid  = blockIdx.x * 256 + threadIdx.x;
    int wid  = gid >> 6;            // 0 .. NB*NN-1
    int lane = threadIdx.x & 63;
    int w    = threadIdx.x >> 6;
    const float* hrow = h + (size_t)wid * FIN;
    float h0 = hrow[lane];
    float h1 = hrow[64 + lane];
    float acc = 0.f;
#pragma unroll
    for (int f = 0; f < 64; ++f) {
        float hf = __shfl(h0, f);
        acc = fmaf(hf, W[f * FOUT + lane], acc);
    }
#pragma unroll
    for (int f = 0; f < 64; ++f) {
        float hf = __shfl(h1, f);
        acc = fmaf(hf, W[(64 + f) * FOUT + lane], acc);
    }
    tbuf[w][lane] = acc;
    float v1 = acc * a[lane];
    float v2 = acc * a[FOUT + lane];
#pragma unroll
    for (int off = 32; off; off >>= 1) {
        v1 += __shfl_xor(v1, off);
        v2 += __shfl_xor(v2, off);
    }
    if (lane == 0) {
        ws[WS_S1 + wid] = v1;
        ws[WS_S2 + wid] = v2;
    }
    __syncthreads();
    // transpose 4 rows x 64 f -> WhT bf16 [b][f][n0..n0+3]
    if (threadIdx.x < 64) {
        int f = threadIdx.x;
        int wid0 = blockIdx.x * 4;
        int b  = wid0 >> 12;         // wid0 / NN
        int n0 = wid0 & (NN - 1);
        unsigned short* whT = (unsigned short*)(ws + WS_WHT);
        uint2 pk;
        pk.x = pack2bf(tbuf[0][f], tbuf[1][f]);
        pk.y = pack2bf(tbuf[2][f], tbuf[3][f]);
        *(uint2*)&whT[(size_t)(b * FOUT + f) * NN + n0] = pk;
    }
}

// K3: fused masked softmax + P@Wh via MFMA. Zero LDS, zero atomics, and the
// adjacency comes from the 2 MB L2-resident bitmask: each lane loads its row's
// 256-j mask chunk ONCE (two uint4) and extracts bits in registers.
// Wave = 16 rows x 256 j; A-fragment built in registers; partials stored
// coalesced to a per-(rowtile,jchunk) slab; k4 reduces.
__global__ __launch_bounds__(256, 4) void k3_attn(float* __restrict__ ws) {
    const int tid  = threadIdx.x;
    const int w    = tid >> 6;
    const int lane = tid & 63;
    const int col  = lane & 15;
    const int quad = lane >> 4;
    const int rt   = blockIdx.x >> 2;            // row-tile 0..255
    const int jc   = (blockIdx.x & 3) * 4 + w;   // j-chunk 0..15
    const int i0   = rt * 16;
    const int jbase = jc * 256;

    const float* __restrict__ s1 = ws + WS_S1;
    const float* __restrict__ s2 = ws + WS_S2;
    const unsigned short* __restrict__ whT = (const unsigned short*)(ws + WS_WHT);
    const unsigned int*  __restrict__ pk  = (const unsigned int*)(ws + WS_PK);

    // packed adj: 8x32-bit words cover this row's 256-j chunk
    const uint4* pw = (const uint4*)(pk + (size_t)(i0 + col) * (NN / 32) + jc * 8);
    uint4 wlo = pw[0], whi = pw[1];
    unsigned int wv[8] = {wlo.x, wlo.y, wlo.z, wlo.w, whi.x, whi.y, whi.z, whi.w};

    float s1a[2];
#pragma unroll
    for (int b = 0; b < 2; ++b) s1a[b] = s1[b * NN + i0 + col];

    f32x4 acc[2][4];        // [batch][nt]
    float lsum[2] = {0.f, 0.f};
#pragma unroll
    for (int b = 0; b < 2; ++b)
#pragma unroll
        for (int nt = 0; nt < 4; ++nt) acc[b][nt] = (f32x4)0.f;

#pragma unroll
    for (int ks = 0; ks < 8; ++ks) {
        const int j8 = jbase + ks * 32 + quad * 8;     // this lane's 8-j base
        const unsigned int mbits = wv[ks] >> (quad * 8);
        float4 a0 = *(const float4*)&s2[j8];
        float4 a1 = *(const float4*)&s2[j8 + 4];
        float4 b0 = *(const float4*)&s2[NN + j8];
        float4 b1 = *(const float4*)&s2[NN + j8 + 4];
        float sj0[8] = {a0.x, a0.y, a0.z, a0.w, a1.x, a1.y, a1.z, a1.w};
        float sj1[8] = {b0.x, b0.y, b0.z, b0.w, b1.x, b1.y, b1.z, b1.w};
        float p0[8], p1[8];
#pragma unroll
        for (int jj = 0; jj < 8; ++jj) {
            bool mm = (mbits >> jj) & 1u;              // shared across batches
            float e0 = s1a[0] + sj0[jj];
            e0 = fmaxf(e0, LALPHA * e0);
            float pe0 = __expf(e0);
            p0[jj] = mm ? pe0 : 0.f;
            lsum[0] += p0[jj];
            float e1 = s1a[1] + sj1[jj];
            e1 = fmaxf(e1, LALPHA * e1);
            float pe1 = __expf(e1);
            p1[jj] = mm ? pe1 : 0.f;
            lsum[1] += p1[jj];
        }
        unsigned int k0[4], k1[4];
#pragma unroll
        for (int q = 0; q < 4; ++q) {
            k0[q] = pack2bf(p0[2 * q], p0[2 * q + 1]);
            k1[q] = pack2bf(p1[2 * q], p1[2 * q + 1]);
        }
        short8 af0 = *(short8*)k0;
        short8 af1 = *(short8*)k1;
#pragma unroll
        for (int nt = 0; nt < 4; ++nt) {
            short8 bf0 = *(const short8*)
                &whT[(size_t)(nt * 16 + col) * NN + j8];
            acc[0][nt] = __builtin_amdgcn_mfma_f32_16x16x32_bf16(
                af0, bf0, acc[0][nt], 0, 0, 0);
            short8 bf1 = *(const short8*)
                &whT[(size_t)(FOUT + nt * 16 + col) * NN + j8];
            acc[1][nt] = __builtin_amdgcn_mfma_f32_16x16x32_bf16(
                af1, bf1, acc[1][nt], 0, 0, 0);
        }
    }

    // ---- epilogue: plain coalesced stores of partials ----
    float* slab = ws + WS_SLAB + (size_t)(rt * NJC + jc) * 2048;
    float* lsl  = ws + WS_LSL  + (size_t)(rt * NJC + jc) * 32;
#pragma unroll
    for (int b = 0; b < 2; ++b) {
        float v = lsum[b];
        v += __shfl_xor(v, 16);
        v += __shfl_xor(v, 32);
        if (quad == 0) lsl[b * 16 + col] = v;
#pragma unroll
        for (int nt = 0; nt < 4; ++nt)
#pragma unroll
            for (int reg = 0; reg < 4; ++reg)
                slab[(((b * 4 + nt) * 4 + reg) << 6) + lane] = acc[b][nt][reg];
    }
}

// K4: reduce NJC partials, out = elu(acc / l). One thread per output element.
__global__ __launch_bounds__(256) void k4_fin(const float* __restrict__ ws,
                                              float* __restrict__ out) {
    int idx = blockIdx.x * 256 + threadIdx.x;    // (b, row, f) flat
    int f   = idx & 63;
    int row = (idx >> 6) & (NN - 1);
    int b   = idx >> 18;
    int rt  = row >> 4;
    int r16 = row & 15;
    int quad = r16 >> 2, reg = r16 & 3;
    int col  = f & 15,  nt  = f >> 4;
    int lane = quad * 16 + col;
    const float* slab = ws + WS_SLAB + (size_t)rt * NJC * 2048
                        + (((b * 4 + nt) * 4 + reg) << 6) + lane;
    const float* lsl  = ws + WS_LSL + (size_t)rt * NJC * 32 + b * 16 + r16;
    float a = 0.f, l = 0.f;
#pragma unroll
    for (int jc = 0; jc < NJC; ++jc) {
        a += slab[jc * 2048];
        l += lsl[jc * 32];
    }
    float v = a / l;
    out[idx] = v > 0.f ? v : (__expf(v) - 1.f);
}

extern "C" void kernel_launch(void* const* d_in, const int* in_sizes, int n_in,
                              void* d_out, int out_size, void* d_ws, size_t ws_size,
                              hipStream_t stream) {
    const float* h   = (const float*)d_in[0];
    const int*   adj = (const int*)d_in[1];
    const float* W   = (const float*)d_in[2];
    const float* a   = (const float*)d_in[3];
    float* ws  = (float*)d_ws;
    float* out = (float*)d_out;

    hipLaunchKernelGGL(k0_pack, dim3(1024),        dim3(256), 0, stream, adj, ws);
    hipLaunchKernelGGL(k1_proj, dim3(NB * NN / 4), dim3(256), 0, stream, h, W, a, ws);
    hipLaunchKernelGGL(k3_attn, dim3(256 * NJC / 4), dim3(256), 0, stream, ws);
    hipLaunchKernelGGL(k4_fin,  dim3(NB * NN * FOUT / 256), dim3(256), 0, stream, ws, out);
}